// Round 1
// baseline (1197.288 us; speedup 1.0000x reference)
//
#include <hip/hip_runtime.h>

// Problem constants (fixed by the reference)
constexpr int Nn  = 100000;   // nodes
constexpr int Ee  = 1600000;  // edges
constexpr int FIN = 128;      // input features
constexpr int Hh  = 32;       // hidden
constexpr int Cc  = 10;       // classes
constexpr int Gg  = 256;      // graphs

__device__ __forceinline__ void atomAddF(float* p, float v) {
    unsafeAtomicAdd(p, v);    // HW global_atomic_add_f32 on gfx950
}

__global__ __launch_bounds__(256) void k_deg(const int* __restrict__ dst, int* __restrict__ deg) {
    int e = blockIdx.x * 256 + threadIdx.x;
    if (e < Ee) atomicAdd(&deg[dst[e]], 1);
}

__global__ __launch_bounds__(256) void k_dinv(const int* __restrict__ deg, float* __restrict__ dinv) {
    int n = blockIdx.x * 256 + threadIdx.x;
    if (n < Nn) dinv[n] = rsqrtf((float)deg[n] + 1.0f);
}

// hl = x @ W  (K = 128). Block = 256 thr = 8 rows x 32 cols. W staged in LDS.
__global__ __launch_bounds__(256) void k_gemm128(const float* __restrict__ x,
                                                 const float* __restrict__ W,
                                                 float* __restrict__ hl) {
    __shared__ float ws[FIN * Hh];
    int tid = threadIdx.x;
#pragma unroll
    for (int i = 0; i < (FIN * Hh) / 256; ++i) ws[tid + 256 * i] = W[tid + 256 * i];
    __syncthreads();
    int row = blockIdx.x * 8 + (tid >> 5);
    int col = tid & 31;
    if (row >= Nn) return;
    const float4* x4 = reinterpret_cast<const float4*>(x + (size_t)row * FIN);
    float acc = 0.f;
#pragma unroll
    for (int k4 = 0; k4 < FIN / 4; ++k4) {
        float4 xv = x4[k4];
        acc = fmaf(xv.x, ws[(4 * k4 + 0) * Hh + col], acc);
        acc = fmaf(xv.y, ws[(4 * k4 + 1) * Hh + col], acc);
        acc = fmaf(xv.z, ws[(4 * k4 + 2) * Hh + col], acc);
        acc = fmaf(xv.w, ws[(4 * k4 + 3) * Hh + col], acc);
    }
    hl[(size_t)row * Hh + col] = acc;
}

// hl = h @ W  (K = 32). Same layout.
__global__ __launch_bounds__(256) void k_gemm32(const float* __restrict__ h,
                                                const float* __restrict__ W,
                                                float* __restrict__ hl) {
    __shared__ float ws[Hh * Hh];
    int tid = threadIdx.x;
    ws[tid]       = W[tid];
    ws[tid + 256] = W[tid + 256];
    ws[tid + 512] = W[tid + 512];
    ws[tid + 768] = W[tid + 768];
    __syncthreads();
    int row = blockIdx.x * 8 + (tid >> 5);
    int col = tid & 31;
    if (row >= Nn) return;
    const float4* h4 = reinterpret_cast<const float4*>(h + (size_t)row * Hh);
    float acc = 0.f;
#pragma unroll
    for (int k4 = 0; k4 < Hh / 4; ++k4) {
        float4 hv = h4[k4];
        acc = fmaf(hv.x, ws[(4 * k4 + 0) * Hh + col], acc);
        acc = fmaf(hv.y, ws[(4 * k4 + 1) * Hh + col], acc);
        acc = fmaf(hv.z, ws[(4 * k4 + 2) * Hh + col], acc);
        acc = fmaf(hv.w, ws[(4 * k4 + 3) * Hh + col], acc);
    }
    hl[(size_t)row * Hh + col] = acc;
}

// agg[dst] += hl[src] * dinv[src]*dinv[dst].  32 lanes per edge (one per col).
__global__ __launch_bounds__(256) void k_edge(const float* __restrict__ hl,
                                              const int* __restrict__ src,
                                              const int* __restrict__ dst,
                                              const float* __restrict__ dinv,
                                              float* __restrict__ agg) {
    long long t = (long long)blockIdx.x * 256 + threadIdx.x;
    int e = (int)(t >> 5);
    int c = (int)(t & 31);
    if (e >= Ee) return;
    int s = src[e], d = dst[e];
    float coef = dinv[s] * dinv[d];
    float v = hl[(size_t)s * Hh + c] * coef;
    atomAddF(&agg[(size_t)d * Hh + c], v);
}

// h_out = relu(agg + hl*dinv^2 + b)
__global__ __launch_bounds__(256) void k_finish(const float* __restrict__ agg,
                                                const float* __restrict__ hl,
                                                const float* __restrict__ dinv,
                                                const float* __restrict__ b,
                                                float* __restrict__ hout) {
    long long t = (long long)blockIdx.x * 256 + threadIdx.x;
    if (t >= (long long)Nn * Hh) return;
    int n = (int)(t >> 5);
    int c = (int)(t & 31);
    float di = dinv[n];
    float v = agg[t] + hl[t] * di * di + b[c];
    hout[t] = fmaxf(v, 0.f);
}

// pooled[batch[n]] += h[n]; cnt[batch[n]] += 1
__global__ __launch_bounds__(256) void k_pool(const float* __restrict__ h,
                                              const int* __restrict__ batch,
                                              float* __restrict__ pooled,
                                              int* __restrict__ cnt) {
    long long t = (long long)blockIdx.x * 256 + threadIdx.x;
    if (t >= (long long)Nn * Hh) return;
    int n = (int)(t >> 5);
    int c = (int)(t & 31);
    int g = batch[n];
    atomAddF(&pooled[(size_t)g * Hh + c], h[t]);
    if (c == 0) atomicAdd(&cnt[g], 1);
}

// MLP head + log_softmax. One block of 256 threads; thread g handles graph g.
__global__ __launch_bounds__(256) void k_head(const float* __restrict__ pooled,
                                              const int* __restrict__ cnt,
                                              const float* __restrict__ Wf1,
                                              const float* __restrict__ bf1,
                                              const float* __restrict__ Wf2,
                                              const float* __restrict__ bf2,
                                              float* __restrict__ out) {
    __shared__ float w1[Hh * Hh];
    __shared__ float w2[Hh * Cc];
    __shared__ float sb1[Hh];
    __shared__ float sb2[Cc];
    int tid = threadIdx.x;
    w1[tid] = Wf1[tid]; w1[tid + 256] = Wf1[tid + 256];
    w1[tid + 512] = Wf1[tid + 512]; w1[tid + 768] = Wf1[tid + 768];
    for (int i = tid; i < Hh * Cc; i += 256) w2[i] = Wf2[i];
    if (tid < Hh) sb1[tid] = bf1[tid];
    if (tid < Cc) sb2[tid] = bf2[tid];
    __syncthreads();

    int g = tid;  // 256 graphs, 256 threads
    float inv = 1.0f / fmaxf((float)cnt[g], 1.0f);
    float p[Hh];
#pragma unroll
    for (int c = 0; c < Hh; ++c) p[c] = pooled[g * Hh + c] * inv;
    float h1[Hh];
#pragma unroll
    for (int j = 0; j < Hh; ++j) {
        float acc = sb1[j];
#pragma unroll
        for (int k = 0; k < Hh; ++k) acc = fmaf(p[k], w1[k * Hh + j], acc);
        h1[j] = fmaxf(acc, 0.f);
    }
    float lg[Cc];
#pragma unroll
    for (int j = 0; j < Cc; ++j) {
        float acc = sb2[j];
#pragma unroll
        for (int k = 0; k < Hh; ++k) acc = fmaf(h1[k], w2[k * Cc + j], acc);
        lg[j] = acc;
    }
    float m = lg[0];
#pragma unroll
    for (int j = 1; j < Cc; ++j) m = fmaxf(m, lg[j]);
    float s = 0.f;
#pragma unroll
    for (int j = 0; j < Cc; ++j) s += __expf(lg[j] - m);
    float lse = m + __logf(s);
#pragma unroll
    for (int j = 0; j < Cc; ++j) out[g * Cc + j] = lg[j] - lse;
}

extern "C" void kernel_launch(void* const* d_in, const int* in_sizes, int n_in,
                              void* d_out, int out_size, void* d_ws, size_t ws_size,
                              hipStream_t stream) {
    const float* x    = (const float*)d_in[0];
    const int*   ei   = (const int*)d_in[1];   // [2, E] -> src = ei, dst = ei + E
    const int*   batch= (const int*)d_in[2];
    const float* W1   = (const float*)d_in[3];
    const float* b1   = (const float*)d_in[4];
    const float* W2   = (const float*)d_in[5];
    const float* b2   = (const float*)d_in[6];
    const float* W3   = (const float*)d_in[7];
    const float* b3   = (const float*)d_in[8];
    const float* W4   = (const float*)d_in[9];
    const float* b4   = (const float*)d_in[10];
    const float* Wf1  = (const float*)d_in[11];
    const float* bf1  = (const float*)d_in[12];
    const float* Wf2  = (const float*)d_in[13];
    const float* bf2  = (const float*)d_in[14];
    float* out = (float*)d_out;

    const int* src = ei;
    const int* dst = ei + Ee;

    // Workspace layout
    char* ws = (char*)d_ws;
    float* hl     = (float*)ws;                          ws += sizeof(float) * Nn * Hh;
    float* hbuf   = (float*)ws;                          ws += sizeof(float) * Nn * Hh;
    float* agg    = (float*)ws;                          ws += sizeof(float) * Nn * Hh;
    float* dinv   = (float*)ws;                          ws += sizeof(float) * Nn;
    int*   deg    = (int*)ws;                            ws += sizeof(int) * Nn;
    float* pooled = (float*)ws;                          ws += sizeof(float) * Gg * Hh;
    int*   cnt    = (int*)ws;                            ws += sizeof(int) * Gg;

    const int nbNodeCol = (Nn * Hh + 255) / 256;   // 12500
    const int nbEdgeCol = (int)(((long long)Ee * 32 + 255) / 256);
    const int nbRows    = (Nn + 7) / 8;            // 12500

    // degrees
    hipMemsetAsync(deg, 0, sizeof(int) * Nn, stream);
    k_deg<<<(Ee + 255) / 256, 256, 0, stream>>>(dst, deg);
    k_dinv<<<(Nn + 255) / 256, 256, 0, stream>>>(deg, dinv);

    // layer 1
    k_gemm128<<<nbRows, 256, 0, stream>>>(x, W1, hl);
    hipMemsetAsync(agg, 0, sizeof(float) * Nn * Hh, stream);
    k_edge<<<nbEdgeCol, 256, 0, stream>>>(hl, src, dst, dinv, agg);
    k_finish<<<nbNodeCol, 256, 0, stream>>>(agg, hl, dinv, b1, hbuf);

    // layers 2..4
    const float* Ws[3] = {W2, W3, W4};
    const float* bs[3] = {b2, b3, b4};
    for (int l = 0; l < 3; ++l) {
        k_gemm32<<<nbRows, 256, 0, stream>>>(hbuf, Ws[l], hl);
        hipMemsetAsync(agg, 0, sizeof(float) * Nn * Hh, stream);
        k_edge<<<nbEdgeCol, 256, 0, stream>>>(hl, src, dst, dinv, agg);
        k_finish<<<nbNodeCol, 256, 0, stream>>>(agg, hl, dinv, bs[l], hbuf);
    }

    // pool + head
    hipMemsetAsync(pooled, 0, sizeof(float) * Gg * Hh, stream);
    hipMemsetAsync(cnt, 0, sizeof(int) * Gg, stream);
    k_pool<<<nbNodeCol, 256, 0, stream>>>(hbuf, batch, pooled, cnt);
    k_head<<<1, 256, 0, stream>>>(pooled, cnt, Wf1, bf1, Wf2, bf2, out);
}

// Round 2
// 683.680 us; speedup vs baseline: 1.7512x; 1.7512x over previous
//
#include <hip/hip_runtime.h>

// Problem constants (fixed by the reference)
constexpr int Nn  = 100000;   // nodes
constexpr int Ee  = 1600000;  // edges
constexpr int FIN = 128;      // input features
constexpr int Hh  = 32;       // hidden
constexpr int Cc  = 10;       // classes
constexpr int Gg  = 256;      // graphs

__device__ __forceinline__ void atomAddF(float* p, float v) {
    unsafeAtomicAdd(p, v);    // HW global_atomic_add_f32 on gfx950
}

// ---------- degree / dinv ----------
__global__ __launch_bounds__(256) void k_deg(const int* __restrict__ dst, int* __restrict__ deg) {
    int e = blockIdx.x * 256 + threadIdx.x;
    if (e < Ee) atomicAdd(&deg[dst[e]], 1);
}

__global__ __launch_bounds__(256) void k_dinv(const int* __restrict__ deg, float* __restrict__ dinv) {
    int n = blockIdx.x * 256 + threadIdx.x;
    if (n < Nn) dinv[n] = rsqrtf((float)deg[n] + 1.0f);
}

// ---------- exclusive scan of deg -> rowptr (3 phases) ----------
// phase 1: per-block (1024 elems) exclusive scan into rowptr, block total to bsum
__global__ __launch_bounds__(256) void k_scan1(const int* __restrict__ deg,
                                               int* __restrict__ rowptr,
                                               int* __restrict__ bsum) {
    __shared__ int sh[256];
    int t = threadIdx.x;
    int base = blockIdx.x * 1024 + t * 4;
    int v0 = (base + 0 < Nn) ? deg[base + 0] : 0;
    int v1 = (base + 1 < Nn) ? deg[base + 1] : 0;
    int v2 = (base + 2 < Nn) ? deg[base + 2] : 0;
    int v3 = (base + 3 < Nn) ? deg[base + 3] : 0;
    int s = v0 + v1 + v2 + v3;
    sh[t] = s;
    __syncthreads();
    for (int off = 1; off < 256; off <<= 1) {
        int x = (t >= off) ? sh[t - off] : 0;
        __syncthreads();
        sh[t] += x;
        __syncthreads();
    }
    int excl = sh[t] - s;
    if (t == 255) bsum[blockIdx.x] = sh[255];
    if (base + 0 < Nn) rowptr[base + 0] = excl;
    if (base + 1 < Nn) rowptr[base + 1] = excl + v0;
    if (base + 2 < Nn) rowptr[base + 2] = excl + v0 + v1;
    if (base + 3 < Nn) rowptr[base + 3] = excl + v0 + v1 + v2;
}

// phase 2: single block scans bsum (NB <= 256) exclusive, in place
__global__ __launch_bounds__(256) void k_scan2(int* __restrict__ bsum, int NB) {
    __shared__ int sh[256];
    int t = threadIdx.x;
    int v = (t < NB) ? bsum[t] : 0;
    sh[t] = v;
    __syncthreads();
    for (int off = 1; off < 256; off <<= 1) {
        int x = (t >= off) ? sh[t - off] : 0;
        __syncthreads();
        sh[t] += x;
        __syncthreads();
    }
    if (t < NB) bsum[t] = sh[t] - v;
}

// phase 3: add block offsets
__global__ __launch_bounds__(256) void k_scan3(int* __restrict__ rowptr, const int* __restrict__ bsum) {
    int i = blockIdx.x * 256 + threadIdx.x;
    if (i < Nn) rowptr[i] += bsum[i >> 10];
}

// ---------- scatter edges into CSR (src index + precomputed coef), packed int2 ----------
__global__ __launch_bounds__(256) void k_scatter(const int* __restrict__ src,
                                                 const int* __restrict__ dst,
                                                 const float* __restrict__ dinv,
                                                 const int* __restrict__ rowptr,
                                                 int* __restrict__ cursor,
                                                 int2* __restrict__ csr) {
    int e = blockIdx.x * 256 + threadIdx.x;
    if (e >= Ee) return;
    int s = src[e], d = dst[e];
    int pos = atomicAdd(&cursor[d], 1);
    int idx = rowptr[d] + pos;
    float coef = dinv[s] * dinv[d];
    csr[idx] = make_int2(s, __float_as_int(coef));
}

// ---------- dense layers ----------
// hl = x @ W  (K = 128). Block = 256 thr = 8 rows x 32 cols. W staged in LDS.
__global__ __launch_bounds__(256) void k_gemm128(const float* __restrict__ x,
                                                 const float* __restrict__ W,
                                                 float* __restrict__ hl) {
    __shared__ float ws[FIN * Hh];
    int tid = threadIdx.x;
#pragma unroll
    for (int i = 0; i < (FIN * Hh) / 256; ++i) ws[tid + 256 * i] = W[tid + 256 * i];
    __syncthreads();
    int row = blockIdx.x * 8 + (tid >> 5);
    int col = tid & 31;
    if (row >= Nn) return;
    const float4* x4 = reinterpret_cast<const float4*>(x + (size_t)row * FIN);
    float acc = 0.f;
#pragma unroll
    for (int k4 = 0; k4 < FIN / 4; ++k4) {
        float4 xv = x4[k4];
        acc = fmaf(xv.x, ws[(4 * k4 + 0) * Hh + col], acc);
        acc = fmaf(xv.y, ws[(4 * k4 + 1) * Hh + col], acc);
        acc = fmaf(xv.z, ws[(4 * k4 + 2) * Hh + col], acc);
        acc = fmaf(xv.w, ws[(4 * k4 + 3) * Hh + col], acc);
    }
    hl[(size_t)row * Hh + col] = acc;
}

// hl = h @ W  (K = 32).
__global__ __launch_bounds__(256) void k_gemm32(const float* __restrict__ h,
                                                const float* __restrict__ W,
                                                float* __restrict__ hl) {
    __shared__ float ws[Hh * Hh];
    int tid = threadIdx.x;
    ws[tid]       = W[tid];
    ws[tid + 256] = W[tid + 256];
    ws[tid + 512] = W[tid + 512];
    ws[tid + 768] = W[tid + 768];
    __syncthreads();
    int row = blockIdx.x * 8 + (tid >> 5);
    int col = tid & 31;
    if (row >= Nn) return;
    const float4* h4 = reinterpret_cast<const float4*>(h + (size_t)row * Hh);
    float acc = 0.f;
#pragma unroll
    for (int k4 = 0; k4 < Hh / 4; ++k4) {
        float4 hv = h4[k4];
        acc = fmaf(hv.x, ws[(4 * k4 + 0) * Hh + col], acc);
        acc = fmaf(hv.y, ws[(4 * k4 + 1) * Hh + col], acc);
        acc = fmaf(hv.z, ws[(4 * k4 + 2) * Hh + col], acc);
        acc = fmaf(hv.w, ws[(4 * k4 + 3) * Hh + col], acc);
    }
    hl[(size_t)row * Hh + col] = acc;
}

// ---------- fused aggregation: gather CSR + self loop + bias + relu ----------
// 32 lanes per node (one per column). No atomics.
__global__ __launch_bounds__(256) void k_agg(const float* __restrict__ hl,
                                             const int2* __restrict__ csr,
                                             const int* __restrict__ rowptr,
                                             const int* __restrict__ deg,
                                             const float* __restrict__ dinv,
                                             const float* __restrict__ b,
                                             float* __restrict__ hout) {
    long long t = (long long)blockIdx.x * 256 + threadIdx.x;
    int n = (int)(t >> 5);
    int col = (int)(t & 31);
    if (n >= Nn) return;
    float di = dinv[n];
    float acc = fmaf(hl[(size_t)n * Hh + col], di * di, b[col]);
    int beg = rowptr[n];
    int end = beg + deg[n];
    for (int i = beg; i < end; ++i) {
        int2 p = csr[i];                       // broadcast within 32-lane group
        float cf = __int_as_float(p.y);
        acc = fmaf(hl[(size_t)p.x * Hh + col], cf, acc);
    }
    hout[(size_t)n * Hh + col] = fmaxf(acc, 0.f);
}

// ---------- segmented mean-pool (batch is sorted) ----------
// One wave handles CH consecutive nodes; lane = (sub: node parity, col).
// Running per-graph sums in registers; atomic flush only on graph change.
constexpr int CH = 256;  // nodes per wave
__global__ __launch_bounds__(256) void k_pool(const float* __restrict__ h,
                                              const int* __restrict__ batch,
                                              float* __restrict__ pooled,
                                              int* __restrict__ cnt) {
    int wid = (blockIdx.x * 256 + threadIdx.x) >> 6;
    int lane = threadIdx.x & 63;
    int col = lane & 31;
    int sub = lane >> 5;
    int n0 = wid * CH;
    if (n0 >= Nn) return;
    int nEnd = min(n0 + CH, Nn);
    float acc = 0.f;
    int gcur = -1, cntLoc = 0;
    for (int n = n0 + sub; n < nEnd; n += 2) {
        int g = batch[n];
        if (g != gcur) {
            if (gcur >= 0) {
                atomAddF(&pooled[gcur * Hh + col], acc);
                if (col == 0) atomicAdd(&cnt[gcur], cntLoc);
            }
            acc = 0.f; cntLoc = 0; gcur = g;
        }
        acc += h[(size_t)n * Hh + col];
        cntLoc++;
    }
    if (gcur >= 0) {
        atomAddF(&pooled[gcur * Hh + col], acc);
        if (col == 0) atomicAdd(&cnt[gcur], cntLoc);
    }
}

// ---------- MLP head + log_softmax ----------
__global__ __launch_bounds__(256) void k_head(const float* __restrict__ pooled,
                                              const int* __restrict__ cnt,
                                              const float* __restrict__ Wf1,
                                              const float* __restrict__ bf1,
                                              const float* __restrict__ Wf2,
                                              const float* __restrict__ bf2,
                                              float* __restrict__ out) {
    __shared__ float w1[Hh * Hh];
    __shared__ float w2[Hh * Cc];
    __shared__ float sb1[Hh];
    __shared__ float sb2[Cc];
    int tid = threadIdx.x;
    w1[tid] = Wf1[tid]; w1[tid + 256] = Wf1[tid + 256];
    w1[tid + 512] = Wf1[tid + 512]; w1[tid + 768] = Wf1[tid + 768];
    for (int i = tid; i < Hh * Cc; i += 256) w2[i] = Wf2[i];
    if (tid < Hh) sb1[tid] = bf1[tid];
    if (tid < Cc) sb2[tid] = bf2[tid];
    __syncthreads();

    int g = tid;
    float inv = 1.0f / fmaxf((float)cnt[g], 1.0f);
    float p[Hh];
#pragma unroll
    for (int c = 0; c < Hh; ++c) p[c] = pooled[g * Hh + c] * inv;
    float h1[Hh];
#pragma unroll
    for (int j = 0; j < Hh; ++j) {
        float acc = sb1[j];
#pragma unroll
        for (int k = 0; k < Hh; ++k) acc = fmaf(p[k], w1[k * Hh + j], acc);
        h1[j] = fmaxf(acc, 0.f);
    }
    float lg[Cc];
#pragma unroll
    for (int j = 0; j < Cc; ++j) {
        float acc = sb2[j];
#pragma unroll
        for (int k = 0; k < Hh; ++k) acc = fmaf(h1[k], w2[k * Cc + j], acc);
        lg[j] = acc;
    }
    float m = lg[0];
#pragma unroll
    for (int j = 1; j < Cc; ++j) m = fmaxf(m, lg[j]);
    float s = 0.f;
#pragma unroll
    for (int j = 0; j < Cc; ++j) s += __expf(lg[j] - m);
    float lse = m + __logf(s);
#pragma unroll
    for (int j = 0; j < Cc; ++j) out[g * Cc + j] = lg[j] - lse;
}

extern "C" void kernel_launch(void* const* d_in, const int* in_sizes, int n_in,
                              void* d_out, int out_size, void* d_ws, size_t ws_size,
                              hipStream_t stream) {
    const float* x    = (const float*)d_in[0];
    const int*   ei   = (const int*)d_in[1];   // [2, E] -> src = ei, dst = ei + E
    const int*   batch= (const int*)d_in[2];
    const float* W1   = (const float*)d_in[3];
    const float* b1   = (const float*)d_in[4];
    const float* W2   = (const float*)d_in[5];
    const float* b2   = (const float*)d_in[6];
    const float* W3   = (const float*)d_in[7];
    const float* b3   = (const float*)d_in[8];
    const float* W4   = (const float*)d_in[9];
    const float* b4   = (const float*)d_in[10];
    const float* Wf1  = (const float*)d_in[11];
    const float* bf1  = (const float*)d_in[12];
    const float* Wf2  = (const float*)d_in[13];
    const float* bf2  = (const float*)d_in[14];
    float* out = (float*)d_out;

    const int* src = ei;
    const int* dst = ei + Ee;

    // Workspace layout (8B-aligned first)
    char* ws = (char*)d_ws;
    int2*  csr    = (int2*)ws;    ws += sizeof(int2) * Ee;        // 12.8 MB
    float* hl     = (float*)ws;   ws += sizeof(float) * Nn * Hh;  // 12.8 MB
    float* hbuf   = (float*)ws;   ws += sizeof(float) * Nn * Hh;  // 12.8 MB
    int*   rowptr = (int*)ws;     ws += sizeof(int) * Nn;
    int*   deg    = (int*)ws;     ws += sizeof(int) * Nn;
    int*   cursor = (int*)ws;     ws += sizeof(int) * Nn;
    float* dinv   = (float*)ws;   ws += sizeof(float) * Nn;
    int*   bsum   = (int*)ws;     ws += sizeof(int) * 256;
    float* pooled = (float*)ws;   ws += sizeof(float) * Gg * Hh;
    int*   cnt    = (int*)ws;     ws += sizeof(int) * Gg;

    const int nbNodeCol = (Nn * Hh + 255) / 256;           // 12500
    const int nbRows    = (Nn + 7) / 8;                    // 12500
    const int nbEdges   = (Ee + 255) / 256;                // 6250
    const int NB1       = (Nn + 1023) / 1024;              // 98

    // ---- graph preprocessing: degrees, dinv, CSR ----
    hipMemsetAsync(deg, 0, sizeof(int) * Nn, stream);
    hipMemsetAsync(cursor, 0, sizeof(int) * Nn, stream);
    k_deg<<<nbEdges, 256, 0, stream>>>(dst, deg);
    k_dinv<<<(Nn + 255) / 256, 256, 0, stream>>>(deg, dinv);
    k_scan1<<<NB1, 256, 0, stream>>>(deg, rowptr, bsum);
    k_scan2<<<1, 256, 0, stream>>>(bsum, NB1);
    k_scan3<<<(Nn + 255) / 256, 256, 0, stream>>>(rowptr, bsum);
    k_scatter<<<nbEdges, 256, 0, stream>>>(src, dst, dinv, rowptr, cursor, csr);

    // ---- layer 1 ----
    k_gemm128<<<nbRows, 256, 0, stream>>>(x, W1, hl);
    k_agg<<<nbNodeCol, 256, 0, stream>>>(hl, csr, rowptr, deg, dinv, b1, hbuf);

    // ---- layers 2..4 ----
    const float* Wsv[3] = {W2, W3, W4};
    const float* bsv[3] = {b2, b3, b4};
    for (int l = 0; l < 3; ++l) {
        k_gemm32<<<nbRows, 256, 0, stream>>>(hbuf, Wsv[l], hl);
        k_agg<<<nbNodeCol, 256, 0, stream>>>(hl, csr, rowptr, deg, dinv, bsv[l], hbuf);
    }

    // ---- pool + head ----
    hipMemsetAsync(pooled, 0, sizeof(float) * Gg * Hh, stream);
    hipMemsetAsync(cnt, 0, sizeof(int) * Gg, stream);
    {
        int waves = (Nn + CH - 1) / CH;
        int blocks = (waves * 64 + 255) / 256;
        k_pool<<<blocks, 256, 0, stream>>>(hbuf, batch, pooled, cnt);
    }
    k_head<<<1, 256, 0, stream>>>(pooled, cnt, Wf1, bf1, Wf2, bf2, out);
}

// Round 3
// 607.000 us; speedup vs baseline: 1.9725x; 1.1263x over previous
//
#include <hip/hip_runtime.h>

// Problem constants (fixed by the reference)
constexpr int Nn  = 100000;   // nodes
constexpr int Ee  = 1600000;  // edges
constexpr int FIN = 128;      // input features
constexpr int Hh  = 32;       // hidden
constexpr int Cc  = 10;       // classes
constexpr int Gg  = 256;      // graphs

__device__ __forceinline__ void atomAddF(float* p, float v) {
    unsafeAtomicAdd(p, v);    // HW global_atomic_add_f32 on gfx950
}

// ---------- degree / dinv ----------
__global__ __launch_bounds__(256) void k_deg(const int* __restrict__ dst, int* __restrict__ deg) {
    int e = blockIdx.x * 256 + threadIdx.x;
    if (e < Ee) atomicAdd(&deg[dst[e]], 1);
}

__global__ __launch_bounds__(256) void k_dinv(const int* __restrict__ deg, float* __restrict__ dinv) {
    int n = blockIdx.x * 256 + threadIdx.x;
    if (n < Nn) dinv[n] = rsqrtf((float)deg[n] + 1.0f);
}

// ---------- exclusive scan of deg -> rowptr (3 phases) ----------
__global__ __launch_bounds__(256) void k_scan1(const int* __restrict__ deg,
                                               int* __restrict__ rowptr,
                                               int* __restrict__ bsum) {
    __shared__ int sh[256];
    int t = threadIdx.x;
    int base = blockIdx.x * 1024 + t * 4;
    int v0 = (base + 0 < Nn) ? deg[base + 0] : 0;
    int v1 = (base + 1 < Nn) ? deg[base + 1] : 0;
    int v2 = (base + 2 < Nn) ? deg[base + 2] : 0;
    int v3 = (base + 3 < Nn) ? deg[base + 3] : 0;
    int s = v0 + v1 + v2 + v3;
    sh[t] = s;
    __syncthreads();
    for (int off = 1; off < 256; off <<= 1) {
        int x = (t >= off) ? sh[t - off] : 0;
        __syncthreads();
        sh[t] += x;
        __syncthreads();
    }
    int excl = sh[t] - s;
    if (t == 255) bsum[blockIdx.x] = sh[255];
    if (base + 0 < Nn) rowptr[base + 0] = excl;
    if (base + 1 < Nn) rowptr[base + 1] = excl + v0;
    if (base + 2 < Nn) rowptr[base + 2] = excl + v0 + v1;
    if (base + 3 < Nn) rowptr[base + 3] = excl + v0 + v1 + v2;
}

__global__ __launch_bounds__(256) void k_scan2(int* __restrict__ bsum, int NB) {
    __shared__ int sh[256];
    int t = threadIdx.x;
    int v = (t < NB) ? bsum[t] : 0;
    sh[t] = v;
    __syncthreads();
    for (int off = 1; off < 256; off <<= 1) {
        int x = (t >= off) ? sh[t - off] : 0;
        __syncthreads();
        sh[t] += x;
        __syncthreads();
    }
    if (t < NB) bsum[t] = sh[t] - v;
}

__global__ __launch_bounds__(256) void k_scan3(int* __restrict__ rowptr, const int* __restrict__ bsum) {
    int i = blockIdx.x * 256 + threadIdx.x;
    if (i < Nn) rowptr[i] += bsum[i >> 10];
}

// ---------- scatter edges into CSR (src index + precomputed coef), packed int2 ----------
__global__ __launch_bounds__(256) void k_scatter(const int* __restrict__ src,
                                                 const int* __restrict__ dst,
                                                 const float* __restrict__ dinv,
                                                 const int* __restrict__ rowptr,
                                                 int* __restrict__ cursor,
                                                 int2* __restrict__ csr) {
    int e = blockIdx.x * 256 + threadIdx.x;
    if (e >= Ee) return;
    int s = src[e], d = dst[e];
    int pos = atomicAdd(&cursor[d], 1);
    int idx = rowptr[d] + pos;
    float coef = dinv[s] * dinv[d];
    csr[idx] = make_int2(s, __float_as_int(coef));
}

// ---------- dense layers ----------
__global__ __launch_bounds__(256) void k_gemm128(const float* __restrict__ x,
                                                 const float* __restrict__ W,
                                                 float* __restrict__ hl) {
    __shared__ float ws[FIN * Hh];
    int tid = threadIdx.x;
#pragma unroll
    for (int i = 0; i < (FIN * Hh) / 256; ++i) ws[tid + 256 * i] = W[tid + 256 * i];
    __syncthreads();
    int row = blockIdx.x * 8 + (tid >> 5);
    int col = tid & 31;
    if (row >= Nn) return;
    const float4* x4 = reinterpret_cast<const float4*>(x + (size_t)row * FIN);
    float acc = 0.f;
#pragma unroll
    for (int k4 = 0; k4 < FIN / 4; ++k4) {
        float4 xv = x4[k4];
        acc = fmaf(xv.x, ws[(4 * k4 + 0) * Hh + col], acc);
        acc = fmaf(xv.y, ws[(4 * k4 + 1) * Hh + col], acc);
        acc = fmaf(xv.z, ws[(4 * k4 + 2) * Hh + col], acc);
        acc = fmaf(xv.w, ws[(4 * k4 + 3) * Hh + col], acc);
    }
    hl[(size_t)row * Hh + col] = acc;
}

__global__ __launch_bounds__(256) void k_gemm32(const float* __restrict__ h,
                                                const float* __restrict__ W,
                                                float* __restrict__ hl) {
    __shared__ float ws[Hh * Hh];
    int tid = threadIdx.x;
    ws[tid]       = W[tid];
    ws[tid + 256] = W[tid + 256];
    ws[tid + 512] = W[tid + 512];
    ws[tid + 768] = W[tid + 768];
    __syncthreads();
    int row = blockIdx.x * 8 + (tid >> 5);
    int col = tid & 31;
    if (row >= Nn) return;
    const float4* h4 = reinterpret_cast<const float4*>(h + (size_t)row * Hh);
    float acc = 0.f;
#pragma unroll
    for (int k4 = 0; k4 < Hh / 4; ++k4) {
        float4 hv = h4[k4];
        acc = fmaf(hv.x, ws[(4 * k4 + 0) * Hh + col], acc);
        acc = fmaf(hv.y, ws[(4 * k4 + 1) * Hh + col], acc);
        acc = fmaf(hv.z, ws[(4 * k4 + 2) * Hh + col], acc);
        acc = fmaf(hv.w, ws[(4 * k4 + 3) * Hh + col], acc);
    }
    hl[(size_t)row * Hh + col] = acc;
}

// ---------- fused aggregation: gather CSR + self loop + bias + relu ----------
// 32 lanes per node (one per column). No atomics. MLP=8 software pipeline:
// load 8 independent csr entries, issue 8 independent row-gathers, accumulate.
__global__ __launch_bounds__(256) void k_agg(const float* __restrict__ hl,
                                             const int2* __restrict__ csr,
                                             const int* __restrict__ rowptr,
                                             const int* __restrict__ deg,
                                             const float* __restrict__ dinv,
                                             const float* __restrict__ b,
                                             float* __restrict__ hout) {
    long long t = (long long)blockIdx.x * 256 + threadIdx.x;
    int n = (int)(t >> 5);
    int col = (int)(t & 31);
    if (n >= Nn) return;
    float di = dinv[n];
    float acc = fmaf(hl[(size_t)n * Hh + col], di * di, b[col]);
    int beg = rowptr[n];
    int end = beg + deg[n];

    int i = beg;
    for (; i + 8 <= end; i += 8) {
        int2 p0 = csr[i + 0];
        int2 p1 = csr[i + 1];
        int2 p2 = csr[i + 2];
        int2 p3 = csr[i + 3];
        int2 p4 = csr[i + 4];
        int2 p5 = csr[i + 5];
        int2 p6 = csr[i + 6];
        int2 p7 = csr[i + 7];
        float v0 = hl[(size_t)p0.x * Hh + col];
        float v1 = hl[(size_t)p1.x * Hh + col];
        float v2 = hl[(size_t)p2.x * Hh + col];
        float v3 = hl[(size_t)p3.x * Hh + col];
        float v4 = hl[(size_t)p4.x * Hh + col];
        float v5 = hl[(size_t)p5.x * Hh + col];
        float v6 = hl[(size_t)p6.x * Hh + col];
        float v7 = hl[(size_t)p7.x * Hh + col];
        acc = fmaf(v0, __int_as_float(p0.y), acc);
        acc = fmaf(v1, __int_as_float(p1.y), acc);
        acc = fmaf(v2, __int_as_float(p2.y), acc);
        acc = fmaf(v3, __int_as_float(p3.y), acc);
        acc = fmaf(v4, __int_as_float(p4.y), acc);
        acc = fmaf(v5, __int_as_float(p5.y), acc);
        acc = fmaf(v6, __int_as_float(p6.y), acc);
        acc = fmaf(v7, __int_as_float(p7.y), acc);
    }
    // remainder (<= 7), keep loads independent too
    if (i < end) {
        int rem = end - i;
        int2 pr[7];
        float vr[7];
        for (int j = 0; j < rem; ++j) pr[j] = csr[i + j];
        for (int j = 0; j < rem; ++j) vr[j] = hl[(size_t)pr[j].x * Hh + col];
        for (int j = 0; j < rem; ++j) acc = fmaf(vr[j], __int_as_float(pr[j].y), acc);
    }
    hout[(size_t)n * Hh + col] = fmaxf(acc, 0.f);
}

// ---------- segmented mean-pool (batch is sorted) ----------
constexpr int CH = 256;  // nodes per wave
__global__ __launch_bounds__(256) void k_pool(const float* __restrict__ h,
                                              const int* __restrict__ batch,
                                              float* __restrict__ pooled,
                                              int* __restrict__ cnt) {
    int wid = (blockIdx.x * 256 + threadIdx.x) >> 6;
    int lane = threadIdx.x & 63;
    int col = lane & 31;
    int sub = lane >> 5;
    int n0 = wid * CH;
    if (n0 >= Nn) return;
    int nEnd = min(n0 + CH, Nn);
    float acc = 0.f;
    int gcur = -1, cntLoc = 0;
    for (int n = n0 + sub; n < nEnd; n += 2) {
        int g = batch[n];
        if (g != gcur) {
            if (gcur >= 0) {
                atomAddF(&pooled[gcur * Hh + col], acc);
                if (col == 0) atomicAdd(&cnt[gcur], cntLoc);
            }
            acc = 0.f; cntLoc = 0; gcur = g;
        }
        acc += h[(size_t)n * Hh + col];
        cntLoc++;
    }
    if (gcur >= 0) {
        atomAddF(&pooled[gcur * Hh + col], acc);
        if (col == 0) atomicAdd(&cnt[gcur], cntLoc);
    }
}

// ---------- MLP head + log_softmax ----------
__global__ __launch_bounds__(256) void k_head(const float* __restrict__ pooled,
                                              const int* __restrict__ cnt,
                                              const float* __restrict__ Wf1,
                                              const float* __restrict__ bf1,
                                              const float* __restrict__ Wf2,
                                              const float* __restrict__ bf2,
                                              float* __restrict__ out) {
    __shared__ float w1[Hh * Hh];
    __shared__ float w2[Hh * Cc];
    __shared__ float sb1[Hh];
    __shared__ float sb2[Cc];
    int tid = threadIdx.x;
    w1[tid] = Wf1[tid]; w1[tid + 256] = Wf1[tid + 256];
    w1[tid + 512] = Wf1[tid + 512]; w1[tid + 768] = Wf1[tid + 768];
    for (int i = tid; i < Hh * Cc; i += 256) w2[i] = Wf2[i];
    if (tid < Hh) sb1[tid] = bf1[tid];
    if (tid < Cc) sb2[tid] = bf2[tid];
    __syncthreads();

    int g = tid;
    float inv = 1.0f / fmaxf((float)cnt[g], 1.0f);
    float p[Hh];
#pragma unroll
    for (int c = 0; c < Hh; ++c) p[c] = pooled[g * Hh + c] * inv;
    float h1[Hh];
#pragma unroll
    for (int j = 0; j < Hh; ++j) {
        float acc = sb1[j];
#pragma unroll
        for (int k = 0; k < Hh; ++k) acc = fmaf(p[k], w1[k * Hh + j], acc);
        h1[j] = fmaxf(acc, 0.f);
    }
    float lg[Cc];
#pragma unroll
    for (int j = 0; j < Cc; ++j) {
        float acc = sb2[j];
#pragma unroll
        for (int k = 0; k < Hh; ++k) acc = fmaf(h1[k], w2[k * Cc + j], acc);
        lg[j] = acc;
    }
    float m = lg[0];
#pragma unroll
    for (int j = 1; j < Cc; ++j) m = fmaxf(m, lg[j]);
    float s = 0.f;
#pragma unroll
    for (int j = 0; j < Cc; ++j) s += __expf(lg[j] - m);
    float lse = m + __logf(s);
#pragma unroll
    for (int j = 0; j < Cc; ++j) out[g * Cc + j] = lg[j] - lse;
}

extern "C" void kernel_launch(void* const* d_in, const int* in_sizes, int n_in,
                              void* d_out, int out_size, void* d_ws, size_t ws_size,
                              hipStream_t stream) {
    const float* x    = (const float*)d_in[0];
    const int*   ei   = (const int*)d_in[1];   // [2, E] -> src = ei, dst = ei + E
    const int*   batch= (const int*)d_in[2];
    const float* W1   = (const float*)d_in[3];
    const float* b1   = (const float*)d_in[4];
    const float* W2   = (const float*)d_in[5];
    const float* b2   = (const float*)d_in[6];
    const float* W3   = (const float*)d_in[7];
    const float* b3   = (const float*)d_in[8];
    const float* W4   = (const float*)d_in[9];
    const float* b4   = (const float*)d_in[10];
    const float* Wf1  = (const float*)d_in[11];
    const float* bf1  = (const float*)d_in[12];
    const float* Wf2  = (const float*)d_in[13];
    const float* bf2  = (const float*)d_in[14];
    float* out = (float*)d_out;

    const int* src = ei;
    const int* dst = ei + Ee;

    // Workspace layout (8B-aligned first)
    char* ws = (char*)d_ws;
    int2*  csr    = (int2*)ws;    ws += sizeof(int2) * Ee;        // 12.8 MB
    float* hl     = (float*)ws;   ws += sizeof(float) * Nn * Hh;  // 12.8 MB
    float* hbuf   = (float*)ws;   ws += sizeof(float) * Nn * Hh;  // 12.8 MB
    int*   rowptr = (int*)ws;     ws += sizeof(int) * Nn;
    int*   deg    = (int*)ws;     ws += sizeof(int) * Nn;
    int*   cursor = (int*)ws;     ws += sizeof(int) * Nn;
    float* dinv   = (float*)ws;   ws += sizeof(float) * Nn;
    int*   bsum   = (int*)ws;     ws += sizeof(int) * 256;
    float* pooled = (float*)ws;   ws += sizeof(float) * Gg * Hh;
    int*   cnt    = (int*)ws;     ws += sizeof(int) * Gg;

    const int nbNodeCol = (Nn * Hh + 255) / 256;           // 12500
    const int nbRows    = (Nn + 7) / 8;                    // 12500
    const int nbEdges   = (Ee + 255) / 256;                // 6250
    const int NB1       = (Nn + 1023) / 1024;              // 98

    // ---- graph preprocessing: degrees, dinv, CSR ----
    hipMemsetAsync(deg, 0, sizeof(int) * Nn, stream);
    hipMemsetAsync(cursor, 0, sizeof(int) * Nn, stream);
    k_deg<<<nbEdges, 256, 0, stream>>>(dst, deg);
    k_dinv<<<(Nn + 255) / 256, 256, 0, stream>>>(deg, dinv);
    k_scan1<<<NB1, 256, 0, stream>>>(deg, rowptr, bsum);
    k_scan2<<<1, 256, 0, stream>>>(bsum, NB1);
    k_scan3<<<(Nn + 255) / 256, 256, 0, stream>>>(rowptr, bsum);
    k_scatter<<<nbEdges, 256, 0, stream>>>(src, dst, dinv, rowptr, cursor, csr);

    // ---- layer 1 ----
    k_gemm128<<<nbRows, 256, 0, stream>>>(x, W1, hl);
    k_agg<<<nbNodeCol, 256, 0, stream>>>(hl, csr, rowptr, deg, dinv, b1, hbuf);

    // ---- layers 2..4 ----
    const float* Wsv[3] = {W2, W3, W4};
    const float* bsv[3] = {b2, b3, b4};
    for (int l = 0; l < 3; ++l) {
        k_gemm32<<<nbRows, 256, 0, stream>>>(hbuf, Wsv[l], hl);
        k_agg<<<nbNodeCol, 256, 0, stream>>>(hl, csr, rowptr, deg, dinv, bsv[l], hbuf);
    }

    // ---- pool + head ----
    hipMemsetAsync(pooled, 0, sizeof(float) * Gg * Hh, stream);
    hipMemsetAsync(cnt, 0, sizeof(int) * Gg, stream);
    {
        int waves = (Nn + CH - 1) / CH;
        int blocks = (waves * 64 + 255) / 256;
        k_pool<<<blocks, 256, 0, stream>>>(hbuf, batch, pooled, cnt);
    }
    k_head<<<1, 256, 0, stream>>>(pooled, cnt, Wf1, bf1, Wf2, bf2, out);
}

// Round 4
// 509.073 us; speedup vs baseline: 2.3519x; 1.1924x over previous
//
#include <hip/hip_runtime.h>

// Problem constants (fixed by the reference)
constexpr int Nn  = 100000;   // nodes
constexpr int Ee  = 1600000;  // edges
constexpr int FIN = 128;      // input features
constexpr int Hh  = 32;       // hidden
constexpr int Cc  = 10;       // classes
constexpr int Gg  = 256;      // graphs

__device__ __forceinline__ void atomAddF(float* p, float v) {
    unsafeAtomicAdd(p, v);    // HW global_atomic_add_f32 on gfx950
}

// ---------- degree / dinv ----------
__global__ __launch_bounds__(256) void k_deg(const int* __restrict__ dst, int* __restrict__ deg) {
    int e = blockIdx.x * 256 + threadIdx.x;
    if (e < Ee) atomicAdd(&deg[dst[e]], 1);
}

__global__ __launch_bounds__(256) void k_dinv(const int* __restrict__ deg, float* __restrict__ dinv) {
    int n = blockIdx.x * 256 + threadIdx.x;
    if (n < Nn) dinv[n] = rsqrtf((float)deg[n] + 1.0f);
}

// ---------- exclusive scan of deg -> rowptr (3 phases) ----------
__global__ __launch_bounds__(256) void k_scan1(const int* __restrict__ deg,
                                               int* __restrict__ rowptr,
                                               int* __restrict__ bsum) {
    __shared__ int sh[256];
    int t = threadIdx.x;
    int base = blockIdx.x * 1024 + t * 4;
    int v0 = (base + 0 < Nn) ? deg[base + 0] : 0;
    int v1 = (base + 1 < Nn) ? deg[base + 1] : 0;
    int v2 = (base + 2 < Nn) ? deg[base + 2] : 0;
    int v3 = (base + 3 < Nn) ? deg[base + 3] : 0;
    int s = v0 + v1 + v2 + v3;
    sh[t] = s;
    __syncthreads();
    for (int off = 1; off < 256; off <<= 1) {
        int x = (t >= off) ? sh[t - off] : 0;
        __syncthreads();
        sh[t] += x;
        __syncthreads();
    }
    int excl = sh[t] - s;
    if (t == 255) bsum[blockIdx.x] = sh[255];
    if (base + 0 < Nn) rowptr[base + 0] = excl;
    if (base + 1 < Nn) rowptr[base + 1] = excl + v0;
    if (base + 2 < Nn) rowptr[base + 2] = excl + v0 + v1;
    if (base + 3 < Nn) rowptr[base + 3] = excl + v0 + v1 + v2;
}

__global__ __launch_bounds__(256) void k_scan2(int* __restrict__ bsum, int NB) {
    __shared__ int sh[256];
    int t = threadIdx.x;
    int v = (t < NB) ? bsum[t] : 0;
    sh[t] = v;
    __syncthreads();
    for (int off = 1; off < 256; off <<= 1) {
        int x = (t >= off) ? sh[t - off] : 0;
        __syncthreads();
        sh[t] += x;
        __syncthreads();
    }
    if (t < NB) bsum[t] = sh[t] - v;
}

// phase 3: add block offsets; also prefill cursor with the final rowptr
__global__ __launch_bounds__(256) void k_scan3(int* __restrict__ rowptr,
                                               const int* __restrict__ bsum,
                                               int* __restrict__ cursor) {
    int i = blockIdx.x * 256 + threadIdx.x;
    if (i < Nn) {
        int v = rowptr[i] + bsum[i >> 10];
        rowptr[i] = v;
        cursor[i] = v;
    }
}

// ---------- scatter edges into CSR (src index only; coef factored out) ----------
__global__ __launch_bounds__(256) void k_scatter(const int* __restrict__ src,
                                                 const int* __restrict__ dst,
                                                 int* __restrict__ cursor,
                                                 int* __restrict__ csr) {
    int e = blockIdx.x * 256 + threadIdx.x;
    if (e >= Ee) return;
    int s = src[e], d = dst[e];
    int idx = atomicAdd(&cursor[d], 1);   // cursor prefilled with rowptr
    csr[idx] = s;
}

// ---------- dense layers (output pre-scaled by dinv[row]) ----------
__global__ __launch_bounds__(256) void k_gemm128(const float* __restrict__ x,
                                                 const float* __restrict__ W,
                                                 const float* __restrict__ dinv,
                                                 float* __restrict__ hls) {
    __shared__ float ws[FIN * Hh];
    int tid = threadIdx.x;
#pragma unroll
    for (int i = 0; i < (FIN * Hh) / 256; ++i) ws[tid + 256 * i] = W[tid + 256 * i];
    __syncthreads();
    int row = blockIdx.x * 8 + (tid >> 5);
    int col = tid & 31;
    if (row >= Nn) return;
    const float4* x4 = reinterpret_cast<const float4*>(x + (size_t)row * FIN);
    float acc = 0.f;
#pragma unroll
    for (int k4 = 0; k4 < FIN / 4; ++k4) {
        float4 xv = x4[k4];
        acc = fmaf(xv.x, ws[(4 * k4 + 0) * Hh + col], acc);
        acc = fmaf(xv.y, ws[(4 * k4 + 1) * Hh + col], acc);
        acc = fmaf(xv.z, ws[(4 * k4 + 2) * Hh + col], acc);
        acc = fmaf(xv.w, ws[(4 * k4 + 3) * Hh + col], acc);
    }
    hls[(size_t)row * Hh + col] = acc * dinv[row];
}

__global__ __launch_bounds__(256) void k_gemm32(const float* __restrict__ h,
                                                const float* __restrict__ W,
                                                const float* __restrict__ dinv,
                                                float* __restrict__ hls) {
    __shared__ float ws[Hh * Hh];
    int tid = threadIdx.x;
    ws[tid]       = W[tid];
    ws[tid + 256] = W[tid + 256];
    ws[tid + 512] = W[tid + 512];
    ws[tid + 768] = W[tid + 768];
    __syncthreads();
    int row = blockIdx.x * 8 + (tid >> 5);
    int col = tid & 31;
    if (row >= Nn) return;
    const float4* h4 = reinterpret_cast<const float4*>(h + (size_t)row * Hh);
    float acc = 0.f;
#pragma unroll
    for (int k4 = 0; k4 < Hh / 4; ++k4) {
        float4 hv = h4[k4];
        acc = fmaf(hv.x, ws[(4 * k4 + 0) * Hh + col], acc);
        acc = fmaf(hv.y, ws[(4 * k4 + 1) * Hh + col], acc);
        acc = fmaf(hv.z, ws[(4 * k4 + 2) * Hh + col], acc);
        acc = fmaf(hv.w, ws[(4 * k4 + 3) * Hh + col], acc);
    }
    hls[(size_t)row * Hh + col] = acc * dinv[row];
}

// ---------- fused aggregation: gather CSR + self loop + bias + relu ----------
// hls is pre-scaled by dinv[src]; out = relu(dinv[n]*(sum + hls[n]) + b).
// 32 lanes per node (one per column). MLP=8, masked 8-wide tail (no scratch).
__global__ __launch_bounds__(256) void k_agg(const float* __restrict__ hls,
                                             const int* __restrict__ csr,
                                             const int* __restrict__ rowptr,
                                             const int* __restrict__ deg,
                                             const float* __restrict__ dinv,
                                             const float* __restrict__ b,
                                             float* __restrict__ hout) {
    long long t = (long long)blockIdx.x * 256 + threadIdx.x;
    int n = (int)(t >> 5);
    int col = (int)(t & 31);
    if (n >= Nn) return;
    int beg = rowptr[n];
    int end = beg + deg[n];
    float acc = 0.f;
    for (int i = beg; i < end; i += 8) {
        int   idx[8];
        float msk[8];
#pragma unroll
        for (int j = 0; j < 8; ++j) {
            int k = i + j;
            int c = csr[k];                 // csr padded by 8 -> always in-bounds
            bool m = (k < end);
            idx[j] = m ? c : n;             // safe gather target when masked
            msk[j] = m ? 1.f : 0.f;
        }
        float v[8];
#pragma unroll
        for (int j = 0; j < 8; ++j) v[j] = hls[(size_t)idx[j] * Hh + col];
#pragma unroll
        for (int j = 0; j < 8; ++j) acc = fmaf(msk[j], v[j], acc);
    }
    float self = hls[(size_t)n * Hh + col];
    float o = fmaf(dinv[n], acc + self, b[col]);
    hout[(size_t)n * Hh + col] = fmaxf(o, 0.f);
}

// ---------- segmented mean-pool (batch is sorted) ----------
constexpr int CH = 256;  // nodes per wave
__global__ __launch_bounds__(256) void k_pool(const float* __restrict__ h,
                                              const int* __restrict__ batch,
                                              float* __restrict__ pooled,
                                              int* __restrict__ cnt) {
    int wid = (blockIdx.x * 256 + threadIdx.x) >> 6;
    int lane = threadIdx.x & 63;
    int col = lane & 31;
    int sub = lane >> 5;
    int n0 = wid * CH;
    if (n0 >= Nn) return;
    int nEnd = min(n0 + CH, Nn);
    float acc = 0.f;
    int gcur = -1, cntLoc = 0;
    for (int n = n0 + sub; n < nEnd; n += 2) {
        int g = batch[n];
        if (g != gcur) {
            if (gcur >= 0) {
                atomAddF(&pooled[gcur * Hh + col], acc);
                if (col == 0) atomicAdd(&cnt[gcur], cntLoc);
            }
            acc = 0.f; cntLoc = 0; gcur = g;
        }
        acc += h[(size_t)n * Hh + col];
        cntLoc++;
    }
    if (gcur >= 0) {
        atomAddF(&pooled[gcur * Hh + col], acc);
        if (col == 0) atomicAdd(&cnt[gcur], cntLoc);
    }
}

// ---------- MLP head + log_softmax ----------
__global__ __launch_bounds__(256) void k_head(const float* __restrict__ pooled,
                                              const int* __restrict__ cnt,
                                              const float* __restrict__ Wf1,
                                              const float* __restrict__ bf1,
                                              const float* __restrict__ Wf2,
                                              const float* __restrict__ bf2,
                                              float* __restrict__ out) {
    __shared__ float w1[Hh * Hh];
    __shared__ float w2[Hh * Cc];
    __shared__ float sb1[Hh];
    __shared__ float sb2[Cc];
    int tid = threadIdx.x;
    w1[tid] = Wf1[tid]; w1[tid + 256] = Wf1[tid + 256];
    w1[tid + 512] = Wf1[tid + 512]; w1[tid + 768] = Wf1[tid + 768];
    for (int i = tid; i < Hh * Cc; i += 256) w2[i] = Wf2[i];
    if (tid < Hh) sb1[tid] = bf1[tid];
    if (tid < Cc) sb2[tid] = bf2[tid];
    __syncthreads();

    int g = tid;
    float inv = 1.0f / fmaxf((float)cnt[g], 1.0f);
    float p[Hh];
#pragma unroll
    for (int c = 0; c < Hh; ++c) p[c] = pooled[g * Hh + c] * inv;
    float h1[Hh];
#pragma unroll
    for (int j = 0; j < Hh; ++j) {
        float acc = sb1[j];
#pragma unroll
        for (int k = 0; k < Hh; ++k) acc = fmaf(p[k], w1[k * Hh + j], acc);
        h1[j] = fmaxf(acc, 0.f);
    }
    float lg[Cc];
#pragma unroll
    for (int j = 0; j < Cc; ++j) {
        float acc = sb2[j];
#pragma unroll
        for (int k = 0; k < Hh; ++k) acc = fmaf(h1[k], w2[k * Cc + j], acc);
        lg[j] = acc;
    }
    float m = lg[0];
#pragma unroll
    for (int j = 1; j < Cc; ++j) m = fmaxf(m, lg[j]);
    float s = 0.f;
#pragma unroll
    for (int j = 0; j < Cc; ++j) s += __expf(lg[j] - m);
    float lse = m + __logf(s);
#pragma unroll
    for (int j = 0; j < Cc; ++j) out[g * Cc + j] = lg[j] - lse;
}

extern "C" void kernel_launch(void* const* d_in, const int* in_sizes, int n_in,
                              void* d_out, int out_size, void* d_ws, size_t ws_size,
                              hipStream_t stream) {
    const float* x    = (const float*)d_in[0];
    const int*   ei   = (const int*)d_in[1];   // [2, E] -> src = ei, dst = ei + E
    const int*   batch= (const int*)d_in[2];
    const float* W1   = (const float*)d_in[3];
    const float* b1   = (const float*)d_in[4];
    const float* W2   = (const float*)d_in[5];
    const float* b2   = (const float*)d_in[6];
    const float* W3   = (const float*)d_in[7];
    const float* b3   = (const float*)d_in[8];
    const float* W4   = (const float*)d_in[9];
    const float* b4   = (const float*)d_in[10];
    const float* Wf1  = (const float*)d_in[11];
    const float* bf1  = (const float*)d_in[12];
    const float* Wf2  = (const float*)d_in[13];
    const float* bf2  = (const float*)d_in[14];
    float* out = (float*)d_out;

    const int* src = ei;
    const int* dst = ei + Ee;

    // Workspace layout (8B-aligned first)
    char* ws = (char*)d_ws;
    float* hl     = (float*)ws;   ws += sizeof(float) * Nn * Hh;   // hls (scaled)
    float* hbuf   = (float*)ws;   ws += sizeof(float) * Nn * Hh;
    int*   csr    = (int*)ws;     ws += sizeof(int) * (Ee + 8);    // +8 pad for masked tail
    int*   rowptr = (int*)ws;     ws += sizeof(int) * Nn;
    int*   deg    = (int*)ws;     ws += sizeof(int) * Nn;
    int*   cursor = (int*)ws;     ws += sizeof(int) * Nn;
    float* dinv   = (float*)ws;   ws += sizeof(float) * Nn;
    int*   bsum   = (int*)ws;     ws += sizeof(int) * 256;
    float* pooled = (float*)ws;   ws += sizeof(float) * Gg * Hh;
    int*   cnt    = (int*)ws;     ws += sizeof(int) * Gg;

    const int nbNodeCol = (Nn * Hh + 255) / 256;           // 12500
    const int nbRows    = (Nn + 7) / 8;                    // 12500
    const int nbEdges   = (Ee + 255) / 256;                // 6250
    const int NB1       = (Nn + 1023) / 1024;              // 98

    // ---- graph preprocessing: degrees, dinv, CSR ----
    hipMemsetAsync(deg, 0, sizeof(int) * Nn, stream);
    k_deg<<<nbEdges, 256, 0, stream>>>(dst, deg);
    k_dinv<<<(Nn + 255) / 256, 256, 0, stream>>>(deg, dinv);
    k_scan1<<<NB1, 256, 0, stream>>>(deg, rowptr, bsum);
    k_scan2<<<1, 256, 0, stream>>>(bsum, NB1);
    k_scan3<<<(Nn + 255) / 256, 256, 0, stream>>>(rowptr, bsum, cursor);
    k_scatter<<<nbEdges, 256, 0, stream>>>(src, dst, cursor, csr);

    // ---- layer 1 ----
    k_gemm128<<<nbRows, 256, 0, stream>>>(x, W1, dinv, hl);
    k_agg<<<nbNodeCol, 256, 0, stream>>>(hl, csr, rowptr, deg, dinv, b1, hbuf);

    // ---- layers 2..4 ----
    const float* Wsv[3] = {W2, W3, W4};
    const float* bsv[3] = {b2, b3, b4};
    for (int l = 0; l < 3; ++l) {
        k_gemm32<<<nbRows, 256, 0, stream>>>(hbuf, Wsv[l], dinv, hl);
        k_agg<<<nbNodeCol, 256, 0, stream>>>(hl, csr, rowptr, deg, dinv, bsv[l], hbuf);
    }

    // ---- pool + head ----
    hipMemsetAsync(pooled, 0, sizeof(float) * Gg * Hh, stream);
    hipMemsetAsync(cnt, 0, sizeof(int) * Gg, stream);
    {
        int waves = (Nn + CH - 1) / CH;
        int blocks = (waves * 64 + 255) / 256;
        k_pool<<<blocks, 256, 0, stream>>>(hbuf, batch, pooled, cnt);
    }
    k_head<<<1, 256, 0, stream>>>(pooled, cnt, Wf1, bf1, Wf2, bf2, out);
}

// Round 5
// 455.171 us; speedup vs baseline: 2.6304x; 1.1184x over previous
//
#include <hip/hip_runtime.h>

// Problem constants (fixed by the reference)
constexpr int Nn  = 100000;   // nodes
constexpr int Ee  = 1600000;  // edges
constexpr int FIN = 128;      // input features
constexpr int Hh  = 32;       // hidden
constexpr int Cc  = 10;       // classes
constexpr int Gg  = 256;      // graphs

constexpr int NXCD   = 8;
constexpr int NRANGE = (Nn + NXCD - 1) / NXCD;   // 12500 nodes per XCD range
constexpr int CHSZ   = 8192;                     // edges per chunk
constexpr int NCHUNK = (Ee + CHSZ - 1) / CHSZ;   // 196

__device__ __forceinline__ void atomAddF(float* p, float v) {
    unsafeAtomicAdd(p, v);    // HW global_atomic_add_f32 on gfx950
}

// ---------- degree / dinv ----------
__global__ __launch_bounds__(256) void k_deg(const int* __restrict__ dst, int* __restrict__ deg) {
    int e = blockIdx.x * 256 + threadIdx.x;
    if (e < Ee) atomicAdd(&deg[dst[e]], 1);
}

__global__ __launch_bounds__(256) void k_dinv(const int* __restrict__ deg, float* __restrict__ dinv) {
    int n = blockIdx.x * 256 + threadIdx.x;
    if (n < Nn) dinv[n] = rsqrtf((float)deg[n] + 1.0f);
}

// ---------- exclusive scan of deg -> rowptr (3 phases) ----------
__global__ __launch_bounds__(256) void k_scan1(const int* __restrict__ deg,
                                               int* __restrict__ rowptr,
                                               int* __restrict__ bsum) {
    __shared__ int sh[256];
    int t = threadIdx.x;
    int base = blockIdx.x * 1024 + t * 4;
    int v0 = (base + 0 < Nn) ? deg[base + 0] : 0;
    int v1 = (base + 1 < Nn) ? deg[base + 1] : 0;
    int v2 = (base + 2 < Nn) ? deg[base + 2] : 0;
    int v3 = (base + 3 < Nn) ? deg[base + 3] : 0;
    int s = v0 + v1 + v2 + v3;
    sh[t] = s;
    __syncthreads();
    for (int off = 1; off < 256; off <<= 1) {
        int x = (t >= off) ? sh[t - off] : 0;
        __syncthreads();
        sh[t] += x;
        __syncthreads();
    }
    int excl = sh[t] - s;
    if (t == 255) bsum[blockIdx.x] = sh[255];
    if (base + 0 < Nn) rowptr[base + 0] = excl;
    if (base + 1 < Nn) rowptr[base + 1] = excl + v0;
    if (base + 2 < Nn) rowptr[base + 2] = excl + v0 + v1;
    if (base + 3 < Nn) rowptr[base + 3] = excl + v0 + v1 + v2;
}

__global__ __launch_bounds__(256) void k_scan2(int* __restrict__ bsum, int NB) {
    __shared__ int sh[256];
    int t = threadIdx.x;
    int v = (t < NB) ? bsum[t] : 0;
    sh[t] = v;
    __syncthreads();
    for (int off = 1; off < 256; off <<= 1) {
        int x = (t >= off) ? sh[t - off] : 0;
        __syncthreads();
        sh[t] += x;
        __syncthreads();
    }
    if (t < NB) bsum[t] = sh[t] - v;
}

// phase 3: add block offsets; also prefill cursor with the final rowptr
__global__ __launch_bounds__(256) void k_scan3(int* __restrict__ rowptr,
                                               const int* __restrict__ bsum,
                                               int* __restrict__ cursor) {
    int i = blockIdx.x * 256 + threadIdx.x;
    if (i < Nn) {
        int v = rowptr[i] + bsum[i >> 10];
        rowptr[i] = v;
        cursor[i] = v;
    }
}

// ---------- XCD-partitioned scatter ----------
// block = (chunk, xcd): processes edges [chunk*CHSZ, ...) but only those whose
// dst lies in this xcd's node range. All writes to a CSR region then come from
// one XCD -> lines accumulate in its L2, single write-back (no cross-XCD
// line ping-pong). blockIdx%8 -> XCD is a locality heuristic only.
__global__ __launch_bounds__(256) void k_scatter(const int* __restrict__ src,
                                                 const int* __restrict__ dst,
                                                 int* __restrict__ cursor,
                                                 int* __restrict__ csr) {
    int xcd   = blockIdx.x & (NXCD - 1);
    int chunk = blockIdx.x >> 3;
    int lo = xcd * NRANGE;
    int hi = lo + NRANGE;
    int e0 = chunk * CHSZ;
    int e1 = min(e0 + CHSZ, Ee);
    for (int e = e0 + threadIdx.x; e < e1; e += 256) {
        int d = dst[e];
        if (d >= lo && d < hi) {
            int s = src[e];
            int idx = atomicAdd(&cursor[d], 1);   // cursor prefilled with rowptr
            csr[idx] = s;
        }
    }
}

// ---------- dense layers (output pre-scaled by dinv[row]) ----------
__global__ __launch_bounds__(256) void k_gemm128(const float* __restrict__ x,
                                                 const float* __restrict__ W,
                                                 const float* __restrict__ dinv,
                                                 float* __restrict__ hls) {
    __shared__ float ws[FIN * Hh];
    int tid = threadIdx.x;
#pragma unroll
    for (int i = 0; i < (FIN * Hh) / 256; ++i) ws[tid + 256 * i] = W[tid + 256 * i];
    __syncthreads();
    int row = blockIdx.x * 8 + (tid >> 5);
    int col = tid & 31;
    if (row >= Nn) return;
    const float4* x4 = reinterpret_cast<const float4*>(x + (size_t)row * FIN);
    float acc = 0.f;
#pragma unroll
    for (int k4 = 0; k4 < FIN / 4; ++k4) {
        float4 xv = x4[k4];
        acc = fmaf(xv.x, ws[(4 * k4 + 0) * Hh + col], acc);
        acc = fmaf(xv.y, ws[(4 * k4 + 1) * Hh + col], acc);
        acc = fmaf(xv.z, ws[(4 * k4 + 2) * Hh + col], acc);
        acc = fmaf(xv.w, ws[(4 * k4 + 3) * Hh + col], acc);
    }
    hls[(size_t)row * Hh + col] = acc * dinv[row];
}

__global__ __launch_bounds__(256) void k_gemm32(const float* __restrict__ h,
                                                const float* __restrict__ W,
                                                const float* __restrict__ dinv,
                                                float* __restrict__ hls) {
    __shared__ float ws[Hh * Hh];
    int tid = threadIdx.x;
    ws[tid]       = W[tid];
    ws[tid + 256] = W[tid + 256];
    ws[tid + 512] = W[tid + 512];
    ws[tid + 768] = W[tid + 768];
    __syncthreads();
    int row = blockIdx.x * 8 + (tid >> 5);
    int col = tid & 31;
    if (row >= Nn) return;
    const float4* h4 = reinterpret_cast<const float4*>(h + (size_t)row * Hh);
    float acc = 0.f;
#pragma unroll
    for (int k4 = 0; k4 < Hh / 4; ++k4) {
        float4 hv = h4[k4];
        acc = fmaf(hv.x, ws[(4 * k4 + 0) * Hh + col], acc);
        acc = fmaf(hv.y, ws[(4 * k4 + 1) * Hh + col], acc);
        acc = fmaf(hv.z, ws[(4 * k4 + 2) * Hh + col], acc);
        acc = fmaf(hv.w, ws[(4 * k4 + 3) * Hh + col], acc);
    }
    hls[(size_t)row * Hh + col] = acc * dinv[row];
}

// ---------- fused aggregation: gather CSR + self loop + bias + relu ----------
__global__ __launch_bounds__(256) void k_agg(const float* __restrict__ hls,
                                             const int* __restrict__ csr,
                                             const int* __restrict__ rowptr,
                                             const int* __restrict__ deg,
                                             const float* __restrict__ dinv,
                                             const float* __restrict__ b,
                                             float* __restrict__ hout) {
    long long t = (long long)blockIdx.x * 256 + threadIdx.x;
    int n = (int)(t >> 5);
    int col = (int)(t & 31);
    if (n >= Nn) return;
    int beg = rowptr[n];
    int end = beg + deg[n];
    float acc = 0.f;
    for (int i = beg; i < end; i += 8) {
        int   idx[8];
        float msk[8];
#pragma unroll
        for (int j = 0; j < 8; ++j) {
            int k = i + j;
            int c = csr[k];                 // csr padded by 8 -> always in-bounds
            bool m = (k < end);
            idx[j] = m ? c : n;             // safe gather target when masked
            msk[j] = m ? 1.f : 0.f;
        }
        float v[8];
#pragma unroll
        for (int j = 0; j < 8; ++j) v[j] = hls[(size_t)idx[j] * Hh + col];
#pragma unroll
        for (int j = 0; j < 8; ++j) acc = fmaf(msk[j], v[j], acc);
    }
    float self = hls[(size_t)n * Hh + col];
    float o = fmaf(dinv[n], acc + self, b[col]);
    hout[(size_t)n * Hh + col] = fmaxf(o, 0.f);
}

// ---------- segmented mean-pool (batch is sorted) ----------
constexpr int CH = 256;  // nodes per wave
__global__ __launch_bounds__(256) void k_pool(const float* __restrict__ h,
                                              const int* __restrict__ batch,
                                              float* __restrict__ pooled,
                                              int* __restrict__ cnt) {
    int wid = (blockIdx.x * 256 + threadIdx.x) >> 6;
    int lane = threadIdx.x & 63;
    int col = lane & 31;
    int sub = lane >> 5;
    int n0 = wid * CH;
    if (n0 >= Nn) return;
    int nEnd = min(n0 + CH, Nn);
    float acc = 0.f;
    int gcur = -1, cntLoc = 0;
    for (int n = n0 + sub; n < nEnd; n += 2) {
        int g = batch[n];
        if (g != gcur) {
            if (gcur >= 0) {
                atomAddF(&pooled[gcur * Hh + col], acc);
                if (col == 0) atomicAdd(&cnt[gcur], cntLoc);
            }
            acc = 0.f; cntLoc = 0; gcur = g;
        }
        acc += h[(size_t)n * Hh + col];
        cntLoc++;
    }
    if (gcur >= 0) {
        atomAddF(&pooled[gcur * Hh + col], acc);
        if (col == 0) atomicAdd(&cnt[gcur], cntLoc);
    }
}

// ---------- MLP head + log_softmax ----------
__global__ __launch_bounds__(256) void k_head(const float* __restrict__ pooled,
                                              const int* __restrict__ cnt,
                                              const float* __restrict__ Wf1,
                                              const float* __restrict__ bf1,
                                              const float* __restrict__ Wf2,
                                              const float* __restrict__ bf2,
                                              float* __restrict__ out) {
    __shared__ float w1[Hh * Hh];
    __shared__ float w2[Hh * Cc];
    __shared__ float sb1[Hh];
    __shared__ float sb2[Cc];
    int tid = threadIdx.x;
    w1[tid] = Wf1[tid]; w1[tid + 256] = Wf1[tid + 256];
    w1[tid + 512] = Wf1[tid + 512]; w1[tid + 768] = Wf1[tid + 768];
    for (int i = tid; i < Hh * Cc; i += 256) w2[i] = Wf2[i];
    if (tid < Hh) sb1[tid] = bf1[tid];
    if (tid < Cc) sb2[tid] = bf2[tid];
    __syncthreads();

    int g = tid;
    float inv = 1.0f / fmaxf((float)cnt[g], 1.0f);
    float p[Hh];
#pragma unroll
    for (int c = 0; c < Hh; ++c) p[c] = pooled[g * Hh + c] * inv;
    float h1[Hh];
#pragma unroll
    for (int j = 0; j < Hh; ++j) {
        float acc = sb1[j];
#pragma unroll
        for (int k = 0; k < Hh; ++k) acc = fmaf(p[k], w1[k * Hh + j], acc);
        h1[j] = fmaxf(acc, 0.f);
    }
    float lg[Cc];
#pragma unroll
    for (int j = 0; j < Cc; ++j) {
        float acc = sb2[j];
#pragma unroll
        for (int k = 0; k < Hh; ++k) acc = fmaf(h1[k], w2[k * Cc + j], acc);
        lg[j] = acc;
    }
    float m = lg[0];
#pragma unroll
    for (int j = 1; j < Cc; ++j) m = fmaxf(m, lg[j]);
    float s = 0.f;
#pragma unroll
    for (int j = 0; j < Cc; ++j) s += __expf(lg[j] - m);
    float lse = m + __logf(s);
#pragma unroll
    for (int j = 0; j < Cc; ++j) out[g * Cc + j] = lg[j] - lse;
}

extern "C" void kernel_launch(void* const* d_in, const int* in_sizes, int n_in,
                              void* d_out, int out_size, void* d_ws, size_t ws_size,
                              hipStream_t stream) {
    const float* x    = (const float*)d_in[0];
    const int*   ei   = (const int*)d_in[1];   // [2, E] -> src = ei, dst = ei + E
    const int*   batch= (const int*)d_in[2];
    const float* W1   = (const float*)d_in[3];
    const float* b1   = (const float*)d_in[4];
    const float* W2   = (const float*)d_in[5];
    const float* b2   = (const float*)d_in[6];
    const float* W3   = (const float*)d_in[7];
    const float* b3   = (const float*)d_in[8];
    const float* W4   = (const float*)d_in[9];
    const float* b4   = (const float*)d_in[10];
    const float* Wf1  = (const float*)d_in[11];
    const float* bf1  = (const float*)d_in[12];
    const float* Wf2  = (const float*)d_in[13];
    const float* bf2  = (const float*)d_in[14];
    float* out = (float*)d_out;

    const int* src = ei;
    const int* dst = ei + Ee;

    // Workspace layout (8B-aligned first)
    char* ws = (char*)d_ws;
    float* hl     = (float*)ws;   ws += sizeof(float) * Nn * Hh;   // hls (scaled)
    float* hbuf   = (float*)ws;   ws += sizeof(float) * Nn * Hh;
    int*   csr    = (int*)ws;     ws += sizeof(int) * (Ee + 8);    // +8 pad for masked tail
    int*   rowptr = (int*)ws;     ws += sizeof(int) * Nn;
    int*   deg    = (int*)ws;     ws += sizeof(int) * Nn;
    int*   cursor = (int*)ws;     ws += sizeof(int) * Nn;
    float* dinv   = (float*)ws;   ws += sizeof(float) * Nn;
    int*   bsum   = (int*)ws;     ws += sizeof(int) * 256;
    float* pooled = (float*)ws;   ws += sizeof(float) * Gg * Hh;
    int*   cnt    = (int*)ws;     ws += sizeof(int) * Gg;

    const int nbNodeCol = (Nn * Hh + 255) / 256;           // 12500
    const int nbRows    = (Nn + 7) / 8;                    // 12500
    const int nbEdges   = (Ee + 255) / 256;                // 6250
    const int NB1       = (Nn + 1023) / 1024;              // 98

    // ---- graph preprocessing: degrees, dinv, CSR ----
    hipMemsetAsync(deg, 0, sizeof(int) * Nn, stream);
    k_deg<<<nbEdges, 256, 0, stream>>>(dst, deg);
    k_dinv<<<(Nn + 255) / 256, 256, 0, stream>>>(deg, dinv);
    k_scan1<<<NB1, 256, 0, stream>>>(deg, rowptr, bsum);
    k_scan2<<<1, 256, 0, stream>>>(bsum, NB1);
    k_scan3<<<(Nn + 255) / 256, 256, 0, stream>>>(rowptr, bsum, cursor);
    k_scatter<<<NCHUNK * NXCD, 256, 0, stream>>>(src, dst, cursor, csr);

    // ---- layer 1 ----
    k_gemm128<<<nbRows, 256, 0, stream>>>(x, W1, dinv, hl);
    k_agg<<<nbNodeCol, 256, 0, stream>>>(hl, csr, rowptr, deg, dinv, b1, hbuf);

    // ---- layers 2..4 ----
    const float* Wsv[3] = {W2, W3, W4};
    const float* bsv[3] = {b2, b3, b4};
    for (int l = 0; l < 3; ++l) {
        k_gemm32<<<nbRows, 256, 0, stream>>>(hbuf, Wsv[l], dinv, hl);
        k_agg<<<nbNodeCol, 256, 0, stream>>>(hl, csr, rowptr, deg, dinv, bsv[l], hbuf);
    }

    // ---- pool + head ----
    hipMemsetAsync(pooled, 0, sizeof(float) * Gg * Hh, stream);
    hipMemsetAsync(cnt, 0, sizeof(int) * Gg, stream);
    {
        int waves = (Nn + CH - 1) / CH;
        int blocks = (waves * 64 + 255) / 256;
        k_pool<<<blocks, 256, 0, stream>>>(hbuf, batch, pooled, cnt);
    }
    k_head<<<1, 256, 0, stream>>>(pooled, cnt, Wf1, bf1, Wf2, bf2, out);
}